// Round 9
// baseline (94.442 us; speedup 1.0000x reference)
//
#include <hip/hip_runtime.h>
#include <hip/hip_bf16.h>

typedef __attribute__((ext_vector_type(8))) short bf16x8;
typedef __attribute__((ext_vector_type(4))) float f32x4;

#define KDIM 2048
#define BK 32
#define NT (KDIM / BK)   // 64 K-tiles

__device__ __forceinline__ unsigned short f2bf(float f) {
  union { float fv; unsigned int u; } c; c.fv = f;
  unsigned int u = c.u;
  unsigned int r = (u + 0x7FFFu + ((u >> 16) & 1u)) >> 16;
  return (unsigned short)r;
}

__device__ __forceinline__ void gload_lds16(const unsigned short* g, unsigned short* l) {
  auto gp = reinterpret_cast<const __attribute__((address_space(1))) unsigned int*>(
      reinterpret_cast<uintptr_t>(g));
  auto lp = reinterpret_cast<__attribute__((address_space(3))) unsigned int*>(
      reinterpret_cast<uintptr_t>(l));
  __builtin_amdgcn_global_load_lds(gp, lp, 16, 0, 0);
}

__device__ __forceinline__ float sigm(float z) { return 1.0f / (1.0f + __expf(-z)); }
__device__ __forceinline__ float tanh_fast(float z) { return 1.0f - 2.0f / (__expf(2.0f * z) + 1.0f); }

// Build hx = [x | h] as bf16 [4096][2048]
__global__ void pack_hx_kernel(const float* __restrict__ x, const float* __restrict__ h,
                               unsigned short* __restrict__ hx) {
  int idx = (blockIdx.x * blockDim.x + threadIdx.x) * 4;
  int row = idx >> 11;
  int col = idx & 2047;
  const float* src = (col < 1024) ? (x + (size_t)row * 1024 + col)
                                  : (h + (size_t)row * 1024 + (col - 1024));
  float4 v = *reinterpret_cast<const float4*>(src);
  ushort4 o = make_ushort4(f2bf(v.x), f2bf(v.y), f2bf(v.z), f2bf(v.w));
  *reinterpret_cast<ushort4*>(hx + idx) = o;
}

// All four W [2048][1024] f32 -> Wt [4][1024][2048] bf16 in one launch (z = gate)
__global__ void transpose_w4_kernel(const float* __restrict__ W0, const float* __restrict__ W1,
                                    const float* __restrict__ W2, const float* __restrict__ W3,
                                    unsigned short* __restrict__ Wt) {
  __shared__ float tile[32][33];
  const int g = blockIdx.z;
  const float* W = (g == 0) ? W0 : (g == 1) ? W1 : (g == 2) ? W2 : W3;
  unsigned short* T = Wt + (size_t)g * 1024 * 2048;
  int n0 = blockIdx.x * 32;
  int k0 = blockIdx.y * 32;
  int tx = threadIdx.x;
  int ty = threadIdx.y;
#pragma unroll
  for (int i = 0; i < 4; ++i)
    tile[ty + 8 * i][tx] = W[(size_t)(k0 + ty + 8 * i) * 1024 + (n0 + tx)];
  __syncthreads();
#pragma unroll
  for (int i = 0; i < 4; ++i)
    T[(size_t)(n0 + ty + 8 * i) * 2048 + (k0 + tx)] = f2bf(tile[tx][ty + 8 * i]);
}

// Fused 4-gate GEMM + LSTM epilogue, sized for 2 blocks/CU (cross-block TLP).
// Block: 256 thr = 4 waves; tile 256 rows x 32 cols x 4 gates; BK=32; LDS 48KB dbuf.
// Grid: 16 brow x 32 bcol = 512 blocks (2 resident per CU).
__global__ __launch_bounds__(256, 2) void lstm_fused_kernel(
    const unsigned short* __restrict__ hx,
    const unsigned short* __restrict__ wtb,
    const float* __restrict__ bias_f,
    const float* __restrict__ bias_i,
    const float* __restrict__ bias_s,
    const float* __restrict__ bias_p,
    const float* __restrict__ c_in,
    float* __restrict__ out) {
  __shared__ unsigned short lA[2][256 * BK];     // 2 x 16 KB
  __shared__ unsigned short lB[2][4 * 32 * BK];  // 2 x 8 KB

  const int tid  = threadIdx.x;
  const int lane = tid & 63;
  const int wid  = tid >> 6;   // 0..3 : 64-row slice
  const int lg   = lane >> 4;  // 0..3
  const int ll   = lane & 15;

  // XCD-aware 2D chunking: xcd = bid%8 (round-robin dispatch), 64 blocks/XCD
  // as an 8 brow x 8 bcol chunk -> working set ~12MB/XCD (L2+L3 served).
  const int xcd = blockIdx.x & 7;
  const int idx = blockIdx.x >> 3;           // 0..63
  const int brow = (xcd >> 2) * 8 + (idx >> 3);  // 0..15
  const int bcol = (xcd & 3) * 8 + (idx & 7);    // 0..31

  // ---- staging descriptors (inverse-swizzled source, linear LDS dest) ----
  // A: 256 rows x 32 k = 1024 slots x 16B ; 4 gloads/thread
  const unsigned short* srcA[4];
  unsigned int dA[4];
#pragma unroll
  for (int i = 0; i < 4; ++i) {
    int s = i * 256 + tid;
    int r = s >> 2, p = s & 3;
    int ch = p ^ (r & 3);
    srcA[i] = hx + (size_t)(brow * 256 + r) * KDIM + ch * 8;
    dA[i] = s * 8;
  }
  // B: 4 gates x 32 cols x 32 k = 512 slots ; 2 gloads/thread
  const unsigned short* srcB[2];
  unsigned int dB[2];
#pragma unroll
  for (int i = 0; i < 2; ++i) {
    int s = i * 256 + tid;
    int rl = s >> 2, p = s & 3;
    int ch = p ^ (rl & 3);
    int g = rl >> 5, col = rl & 31;
    srcB[i] = wtb + (size_t)g * 1024 * 2048 + (size_t)(bcol * 32 + col) * KDIM + ch * 8;
    dB[i] = s * 8;
  }

  // ---- fragment LDS element offsets (row&3 == ll&3) ----
  const int fch = lg ^ (ll & 3);
  unsigned int aoff[4];
#pragma unroll
  for (int m = 0; m < 4; ++m)
    aoff[m] = (unsigned)((wid * 64 + m * 16 + ll) * BK + fch * 8);
  unsigned int boff[8];
#pragma unroll
  for (int gn = 0; gn < 8; ++gn)
    boff[gn] = (unsigned)((gn * 16 + ll) * BK + fch * 8);

  f32x4 acc[4][8];
#pragma unroll
  for (int m = 0; m < 4; ++m)
#pragma unroll
    for (int gn = 0; gn < 8; ++gn)
      acc[m][gn] = (f32x4)(0.0f);

  // ---- prologue: stage tile 0 into buf0 ----
#pragma unroll
  for (int i = 0; i < 4; ++i) gload_lds16(srcA[i], &lA[0][dA[i]]);
#pragma unroll
  for (int i = 0; i < 2; ++i) gload_lds16(srcB[i], &lB[0][dB[i]]);
#pragma unroll
  for (int i = 0; i < 4; ++i) srcA[i] += BK;
#pragma unroll
  for (int i = 0; i < 2; ++i) srcB[i] += BK;
  __syncthreads();

  for (int t = 0; t < NT; ++t) {
    const int cur = t & 1;
    const int nxt = cur ^ 1;

    // stage next tile first (HBM latency hides under this tile's compute)
    if (t < NT - 1) {
#pragma unroll
      for (int i = 0; i < 4; ++i) gload_lds16(srcA[i], &lA[nxt][dA[i]]);
#pragma unroll
      for (int i = 0; i < 2; ++i) gload_lds16(srcB[i], &lB[nxt][dB[i]]);
#pragma unroll
      for (int i = 0; i < 4; ++i) srcA[i] += BK;
#pragma unroll
      for (int i = 0; i < 2; ++i) srcB[i] += BK;
    }

    // read fragments + MFMA
    bf16x8 aF[4], bF[8];
#pragma unroll
    for (int m = 0; m < 4; ++m)
      aF[m] = *reinterpret_cast<const bf16x8*>(&lA[cur][aoff[m]]);
#pragma unroll
    for (int gn = 0; gn < 8; ++gn)
      bF[gn] = *reinterpret_cast<const bf16x8*>(&lB[cur][boff[gn]]);

    __builtin_amdgcn_s_setprio(1);
#pragma unroll
    for (int m = 0; m < 4; ++m)
#pragma unroll
      for (int gn = 0; gn < 8; ++gn)
        acc[m][gn] = __builtin_amdgcn_mfma_f32_16x16x32_bf16(aF[m], bF[gn], acc[m][gn], 0, 0, 0);
    __builtin_amdgcn_s_setprio(0);

    // one barrier per tile: drains staging (vmcnt) + all waves done reading cur
    __syncthreads();
  }

  // ---- epilogue: gates + cell update, store h_new (coalesced) ----
  const int row0 = brow * 256 + wid * 64;
  const int col0 = bcol * 32;
  float bv[4][2];
#pragma unroll
  for (int n = 0; n < 2; ++n) {
    int col = col0 + n * 16 + ll;
    bv[0][n] = bias_f[col];
    bv[1][n] = bias_i[col];
    bv[2][n] = bias_s[col];
    bv[3][n] = bias_p[col];
  }
#pragma unroll
  for (int m = 0; m < 4; ++m)
#pragma unroll
    for (int n = 0; n < 2; ++n)
#pragma unroll
      for (int j = 0; j < 4; ++j) {
        int row = row0 + m * 16 + lg * 4 + j;
        int col = col0 + n * 16 + ll;
        float zf = acc[m][0 + n][j] + bv[0][n];
        float zi = acc[m][2 + n][j] + bv[1][n];
        float zs = acc[m][4 + n][j] + bv[2][n];
        float zp = acc[m][6 + n][j] + bv[3][n];
        float fg = sigm(zf);
        float ig = sigm(zi);
        float sg = sigm(zs);
        float pg = tanh_fast(zp);
        float cn = c_in[(size_t)row * 1024 + col] * fg + ig * pg;
        out[(size_t)row * 1024 + col] = tanh_fast(cn) * sg;
      }
}

extern "C" void kernel_launch(void* const* d_in, const int* in_sizes, int n_in,
                              void* d_out, int out_size, void* d_ws, size_t ws_size,
                              hipStream_t stream) {
  const float* x  = (const float*)d_in[0];
  const float* h  = (const float*)d_in[1];
  const float* c  = (const float*)d_in[2];
  const float* Wf = (const float*)d_in[3];
  const float* bf = (const float*)d_in[4];
  const float* Wi = (const float*)d_in[5];
  const float* bi = (const float*)d_in[6];
  const float* Ws = (const float*)d_in[7];
  const float* bs = (const float*)d_in[8];
  const float* Wp = (const float*)d_in[9];
  const float* bp = (const float*)d_in[10];
  float* out = (float*)d_out;

  unsigned short* ws = (unsigned short*)d_ws;
  unsigned short* hx  = ws;                        // 4096*2048 bf16 = 16 MB
  unsigned short* wtb = ws + (size_t)4096 * 2048;  // 4*1024*2048 bf16 = 16 MB

  pack_hx_kernel<<<(4096 * 2048 / 4) / 256, 256, 0, stream>>>(x, h, hx);

  dim3 tb(32, 8);
  dim3 tg(1024 / 32, 2048 / 32, 4);
  transpose_w4_kernel<<<tg, tb, 0, stream>>>(Wf, Wi, Ws, Wp, wtb);

  lstm_fused_kernel<<<512, 256, 0, stream>>>(hx, wtb, bf, bi, bs, bp, c, out);
}

// Round 10
// 88.781 us; speedup vs baseline: 1.0638x; 1.0638x over previous
//
#include <hip/hip_runtime.h>
#include <hip/hip_bf16.h>

typedef __attribute__((ext_vector_type(8))) short bf16x8;
typedef __attribute__((ext_vector_type(4))) float f32x4;

#define KDIM 2048
#define BK 64
#define NT (KDIM / BK)          // 32 K-tiles
#define TSTRIDE 524288          // bytes between K-tiles in packed W

__device__ __forceinline__ unsigned short f2bf(float f) {
  union { float fv; unsigned int u; } c; c.fv = f;
  unsigned int u = c.u;
  unsigned int r = (u + 0x7FFFu + ((u >> 16) & 1u)) >> 16;
  return (unsigned short)r;
}

__device__ __forceinline__ void gload_lds16(const unsigned short* g, unsigned short* l) {
  auto gp = reinterpret_cast<const __attribute__((address_space(1))) unsigned int*>(
      reinterpret_cast<uintptr_t>(g));
  auto lp = reinterpret_cast<__attribute__((address_space(3))) unsigned int*>(
      reinterpret_cast<uintptr_t>(l));
  __builtin_amdgcn_global_load_lds(gp, lp, 16, 0, 0);
}

__device__ __forceinline__ float sigm(float z) { return 1.0f / (1.0f + __expf(-z)); }
__device__ __forceinline__ float tanh_fast(float z) { return 1.0f - 2.0f / (__expf(2.0f * z) + 1.0f); }

#define BAR  asm volatile("s_barrier" ::: "memory")
#define VMC16 asm volatile("s_waitcnt vmcnt(16)" ::: "memory")

// Build hx = [x | h] as bf16 [4096][2048]
__global__ void pack_hx_kernel(const float* __restrict__ x, const float* __restrict__ h,
                               unsigned short* __restrict__ hx) {
  int idx = (blockIdx.x * blockDim.x + threadIdx.x) * 4;
  int row = idx >> 11;
  int col = idx & 2047;
  const float* src = (col < 1024) ? (x + (size_t)row * 1024 + col)
                                  : (h + (size_t)row * 1024 + (col - 1024));
  float4 v = *reinterpret_cast<const float4*>(src);
  ushort4 o = make_ushort4(f2bf(v.x), f2bf(v.y), f2bf(v.z), f2bf(v.w));
  *reinterpret_cast<ushort4*>(hx + idx) = o;
}

// W[g] [2048][1024] f32 -> fragment-packed bf16:
// wtp frag index = (((kt*4 + g)*64 + gcf)*2 + ks)*64 + lane  (16B per frag)
// frag value: 8 bf16 = W[k = kt*64+ks*32+(lane>>4)*8 + j][col = gcf*16 + (lane&15)]
__global__ void transpose_w4_kernel(const float* __restrict__ W0, const float* __restrict__ W1,
                                    const float* __restrict__ W2, const float* __restrict__ W3,
                                    unsigned short* __restrict__ wtp) {
  __shared__ float tile[32][33];
  const int g = blockIdx.z;
  const float* W = (g == 0) ? W0 : (g == 1) ? W1 : (g == 2) ? W2 : W3;
  int n0 = blockIdx.x * 32;   // col block
  int k0 = blockIdx.y * 32;   // k block
  int tx = threadIdx.x;       // 0..31
  int ty = threadIdx.y;       // 0..7
#pragma unroll
  for (int i = 0; i < 4; ++i)
    tile[ty + 8 * i][tx] = W[(size_t)(k0 + ty + 8 * i) * 1024 + (n0 + tx)];
  __syncthreads();
  int tid = ty * 32 + tx;
  if (tid < 128) {
    int col16 = tid & 15;
    int j2 = (tid >> 4) & 3;
    int gcf_sub = tid >> 6;             // 0..1
    int gcf = (n0 >> 4) + gcf_sub;
    int kt = k0 >> 6;
    int ks = (k0 >> 5) & 1;
    int lane = j2 * 16 + col16;
    bf16x8 v;
#pragma unroll
    for (int j = 0; j < 8; ++j)
      v[j] = (short)f2bf(tile[j2 * 8 + j][gcf_sub * 16 + col16]);
    size_t cid = ((((size_t)kt * 4 + g) * 64 + gcf) * 2 + ks) * 64 + lane;
    *reinterpret_cast<bf16x8*>(wtp + cid * 8) = v;
  }
}

// Fused 4-gate GEMM + LSTM epilogue. A via LDS dbuf; B direct global->VGPR (flatmm).
// Grid: 256 blocks (1/CU), 512 threads (8 waves, 4M x 2N; wave = 64 rows x 32 cols x 4 gates).
__global__ __launch_bounds__(512, 2) void lstm_fused_kernel(
    const unsigned short* __restrict__ hx,
    const unsigned short* __restrict__ wtp,
    const float* __restrict__ bias_f,
    const float* __restrict__ bias_i,
    const float* __restrict__ bias_s,
    const float* __restrict__ bias_p,
    const float* __restrict__ c_in,
    float* __restrict__ out) {
  __shared__ unsigned short lA[2][256 * BK];  // 2 x 32 KB (A only)

  const int tid  = threadIdx.x;
  const int lane = tid & 63;
  const int wid  = tid >> 6;
  const int wr   = wid >> 1;  // 0..3 : 64-row slice
  const int wc   = wid & 1;   // 0..1 : 32-col slice
  const int lg   = lane >> 4;
  const int ll   = lane & 15;

  // bijective XCD swizzle (256 % 8 == 0)
  const int wg   = (blockIdx.x & 7) * 32 + (blockIdx.x >> 3);
  const int brow = wg >> 4;  // 0..15
  const int bcol = wg & 15;  // 0..15

  // ---- A staging descriptors (inverse-swizzled source, linear LDS dest) ----
  const unsigned short* srcA[4];
  unsigned int dA[4];
#pragma unroll
  for (int i = 0; i < 4; ++i) {
    int s = i * 512 + tid;
    int r = s >> 3, sch = s & 7;
    int ch = sch ^ (r & 7);
    srcA[i] = hx + (size_t)(brow * 256 + r) * KDIM + ch * 8;
    dA[i] = s * 8;
  }

  // ---- B per-gate per-lane pointers into packed weights ----
  const char* gp[4];
#pragma unroll
  for (int g = 0; g < 4; ++g)
    gp[g] = reinterpret_cast<const char*>(wtp) +
            (size_t)16 * ((size_t)(g * 64 + bcol * 4 + wc * 2) * 128 + lane);
  // per-load imm offset: n*2048 + ks*1024 ; per tile advance: +TSTRIDE

  // ---- A fragment LDS element offsets: base(ks) + m*1024 ----
  const unsigned eA0 = (unsigned)((wr * 64 + ll) * 64 + ((0 * 4 + lg) ^ (ll & 7)) * 8);
  const unsigned eA1 = (unsigned)((wr * 64 + ll) * 64 + ((1 * 4 + lg) ^ (ll & 7)) * 8);

  f32x4 acc[4][4][2];
#pragma unroll
  for (int g = 0; g < 4; ++g)
#pragma unroll
    for (int m = 0; m < 4; ++m)
#pragma unroll
      for (int n = 0; n < 2; ++n)
        acc[g][m][n] = (f32x4)(0.0f);

  bf16x8 bF[4][2][2];  // [g][n][ks] — rotated in place each tile

  // ---- prologue: stage A(0) (pinned), load B(0), retire A(0), barrier ----
  __builtin_amdgcn_sched_barrier(0);
#pragma unroll
  for (int i = 0; i < 4; ++i) gload_lds16(srcA[i], &lA[0][dA[i]]);
  __builtin_amdgcn_sched_barrier(0);
#pragma unroll
  for (int i = 0; i < 4; ++i) srcA[i] += BK;
#pragma unroll
  for (int g = 0; g < 4; ++g) {
#pragma unroll
    for (int n = 0; n < 2; ++n)
#pragma unroll
      for (int ks = 0; ks < 2; ++ks)
        bF[g][n][ks] = *reinterpret_cast<const bf16x8*>(gp[g] + n * 2048 + ks * 1024);
    gp[g] += TSTRIDE;
  }
  VMC16;  // queue = [A(0) x4, B(0) x16] -> retire A(0) (own-wave), then barrier for all waves
  BAR;

  for (int t = 0; t < NT; ++t) {
    const unsigned short* Ab = &lA[t & 1][0];
    unsigned short* An = &lA[(t + 1) & 1][0];
    const bool more = (t + 1 < NT);

    // stage A(t+1) into the other buffer (pinned so it's oldest in this tile's queue)
    if (more) {
      __builtin_amdgcn_sched_barrier(0);
#pragma unroll
      for (int i = 0; i < 4; ++i) gload_lds16(srcA[i], An + dA[i]);
      __builtin_amdgcn_sched_barrier(0);
#pragma unroll
      for (int i = 0; i < 4; ++i) srcA[i] += BK;
    }

    // A fragments for this tile
    bf16x8 aF[4][2];
#pragma unroll
    for (int m = 0; m < 4; ++m) {
      aF[m][0] = *reinterpret_cast<const bf16x8*>(Ab + eA0 + m * 1024);
      aF[m][1] = *reinterpret_cast<const bf16x8*>(Ab + eA1 + m * 1024);
    }

    // gates: MFMA on bF[g](t), then rotate-in bF[g](t+1)
#pragma unroll
    for (int g = 0; g < 4; ++g) {
      __builtin_amdgcn_s_setprio(1);
#pragma unroll
      for (int m = 0; m < 4; ++m)
#pragma unroll
        for (int n = 0; n < 2; ++n)
#pragma unroll
          for (int ks = 0; ks < 2; ++ks)
            acc[g][m][n] = __builtin_amdgcn_mfma_f32_16x16x32_bf16(
                aF[m][ks], bF[g][n][ks], acc[g][m][n], 0, 0, 0);
      __builtin_amdgcn_s_setprio(0);
      if (more) {
#pragma unroll
        for (int n = 0; n < 2; ++n)
#pragma unroll
          for (int ks = 0; ks < 2; ++ks)
            bF[g][n][ks] = *reinterpret_cast<const bf16x8*>(gp[g] + n * 2048 + ks * 1024);
        gp[g] += TSTRIDE;
      }
    }

    if (more) {
      VMC16;  // queue = [A(t+1) x4, B(t+1) x16] -> retire own A(t+1)
      BAR;    // all waves' A(t+1) retired; A(t) reads done -> dbuf safe
    }
  }

  // ---- epilogue: gates + cell update, store h_new (coalesced) ----
  const int row0 = brow * 256 + wr * 64;
  const int col0 = bcol * 64 + wc * 32;
  float bv[4][2];
#pragma unroll
  for (int n = 0; n < 2; ++n) {
    int col = col0 + n * 16 + ll;
    bv[0][n] = bias_f[col];
    bv[1][n] = bias_i[col];
    bv[2][n] = bias_s[col];
    bv[3][n] = bias_p[col];
  }
#pragma unroll
  for (int m = 0; m < 4; ++m)
#pragma unroll
    for (int n = 0; n < 2; ++n)
#pragma unroll
      for (int j = 0; j < 4; ++j) {
        int row = row0 + m * 16 + lg * 4 + j;
        int col = col0 + n * 16 + ll;
        float zf = acc[0][m][n][j] + bv[0][n];
        float zi = acc[1][m][n][j] + bv[1][n];
        float zs = acc[2][m][n][j] + bv[2][n];
        float zp = acc[3][m][n][j] + bv[3][n];
        float fg = sigm(zf);
        float ig = sigm(zi);
        float sg = sigm(zs);
        float pg = tanh_fast(zp);
        float cn = c_in[(size_t)row * 1024 + col] * fg + ig * pg;
        out[(size_t)row * 1024 + col] = tanh_fast(cn) * sg;
      }
}

extern "C" void kernel_launch(void* const* d_in, const int* in_sizes, int n_in,
                              void* d_out, int out_size, void* d_ws, size_t ws_size,
                              hipStream_t stream) {
  const float* x  = (const float*)d_in[0];
  const float* h  = (const float*)d_in[1];
  const float* c  = (const float*)d_in[2];
  const float* Wf = (const float*)d_in[3];
  const float* bf = (const float*)d_in[4];
  const float* Wi = (const float*)d_in[5];
  const float* bi = (const float*)d_in[6];
  const float* Ws = (const float*)d_in[7];
  const float* bs = (const float*)d_in[8];
  const float* Wp = (const float*)d_in[9];
  const float* bp = (const float*)d_in[10];
  float* out = (float*)d_out;

  unsigned short* ws = (unsigned short*)d_ws;
  unsigned short* hx  = ws;                        // 4096*2048 bf16 = 16 MB
  unsigned short* wtp = ws + (size_t)4096 * 2048;  // packed weights, 16 MB

  pack_hx_kernel<<<(4096 * 2048 / 4) / 256, 256, 0, stream>>>(x, h, hx);

  dim3 tb(32, 8);
  dim3 tg(1024 / 32, 2048 / 32, 4);
  transpose_w4_kernel<<<tg, tb, 0, stream>>>(Wf, Wi, Ws, Wp, wtp);

  lstm_fused_kernel<<<256, 512, 0, stream>>>(hx, wtp, bf, bi, bs, bp, c, out);
}